// Round 4
// baseline (482.445 us; speedup 1.0000x reference)
//
#include <hip/hip_runtime.h>

// Shapes (fixed): B=16, T_his=4095, T=4096, hid=2048, H=16, dh=128
// d_out layout (f32): K_out [16][4096][2048] | V_out [16][4096][2048] | v_next [16][2048]
// K_out[b][h*256 + t/16][(t%16)*128 + d] = K[b][t][h*128+d], K = concat(K_his, k_new)
// v_next = (sum_t V[b,t,:]) @ W_proj + b_proj   (softmax over size-1 axis == ones; q dead)

typedef float f4 __attribute__((ext_vector_type(4)));

__global__ void init_kernel(const float* __restrict__ b_attn,
                            const float* __restrict__ b_proj,
                            float* __restrict__ qkv,      // [16][4096] (k | v)
                            float* __restrict__ colsum,   // [16][2048]
                            float* __restrict__ vnext) {  // [16][2048] in d_out
  int tid = blockIdx.x * blockDim.x + threadIdx.x;   // 65536 threads
  qkv[tid] = b_attn[2048 + (tid & 4095)];            // bias for k,v columns
  if (tid < 32768) {
    colsum[tid] = 0.0f;
    vnext[tid] = b_proj[tid & 2047];
  }
}

// Partial GEMM: out[b][j] += X[16][2048] @ W[2048][ldw] (cols col0..col0+ncols)
__global__ void small_gemm_atomic(const float* __restrict__ X,
                                  const float* __restrict__ W,
                                  int ldw, int col0,
                                  float* __restrict__ out, int ncols) {
  int j  = blockIdx.x * 512 + threadIdx.x * 2;
  int k0 = blockIdx.y * 64;
  const float* wp = W + (size_t)k0 * ldw + col0 + j;
  float2 acc[16];
#pragma unroll
  for (int b = 0; b < 16; ++b) acc[b] = make_float2(0.f, 0.f);
  for (int kk = 0; kk < 64; ++kk) {
    float2 w = *(const float2*)(wp + (size_t)kk * ldw);
    const float* xp = X + k0 + kk;
#pragma unroll
    for (int b = 0; b < 16; ++b) {
      float xv = xp[(size_t)b * 2048];
      acc[b].x = fmaf(xv, w.x, acc[b].x);
      acc[b].y = fmaf(xv, w.y, acc[b].y);
    }
  }
#pragma unroll
  for (int b = 0; b < 16; ++b) {
    atomicAdd(&out[b * ncols + j],     acc[b].x);
    atomicAdd(&out[b * ncols + j + 1], acc[b].y);
  }
}

// Streaming head-major transpose via LDS staging.
// grid = (32 t-groups of 128, 16 batches, 2 {K,V}), block = 256, 32 KB LDS.
// Phase p (0..31): stage rows t = gx*128 + p*4 .. +3 (contiguous 32 KB read),
// then emit the matching 2 KB slice of each of 16 head-rows (contiguous writes).
__global__ void __launch_bounds__(256, 4)
copy_transpose(const float* __restrict__ K_his,
               const float* __restrict__ V_his,
               const float* __restrict__ qkv,   // [16][4096] (k|v)
               float* __restrict__ out,
               float* __restrict__ colsum) {
  const int b     = blockIdx.y;
  const int which = blockIdx.z;                 // 0=K, 1=V
  const int gx    = blockIdx.x;                 // t-block: 128 t's
  const int tid   = threadIdx.x;
  const int tbase = gx * 128;

  const float* src  = which ? V_his : K_his;
  const float* srcb = src + (size_t)b * 8386560ull;          // 4095*2048
  const float* qsrc = qkv + b * 4096 + which * 2048;         // appended row
  float* outb = out + ((size_t)which << 27) + ((size_t)b << 23);

  __shared__ float lds[8192];                   // 4 rows x 2048

  f4 acc0 = {0.f, 0.f, 0.f, 0.f};              // channel tid*4
  f4 acc1 = {0.f, 0.f, 0.f, 0.f};              // channel 1024 + tid*4
  const int c0 = tid * 4;
  const int c1 = 1024 + tid * 4;

  const int o    = (tid & 127) * 4;            // offset within 512-float h-chunk
  const int s_l  = o >> 7;                     // local row 0..3
  const int d    = o & 127;
  const int hsel = tid >> 7;                   // 0/1: which of the pass's 2 heads

  for (int p = 0; p < 32; ++p) {
    // ---- phase 1: contiguous load of 4 rows -> LDS, accumulate colsum ----
    f4 v[8];
#pragma unroll
    for (int j = 0; j < 8; ++j) {
      const int r = j >> 1;
      const int c = (j & 1) ? c1 : c0;
      const int t = tbase + p * 4 + r;
      const float* pr = (t == 4095) ? qsrc : (srcb + (size_t)t * 2048u);
      v[j] = __builtin_nontemporal_load((const f4*)(pr + c));
    }
#pragma unroll
    for (int j = 0; j < 8; ++j)
      *(f4*)(&lds[(j * 256 + tid) * 4]) = v[j];
    if (which) {
#pragma unroll
      for (int j = 0; j < 8; j += 2) { acc0 += v[j]; acc1 += v[j + 1]; }
    }
    __syncthreads();

    // ---- phase 2: head-major contiguous writes ----
    const int tgrp = gx * 8 + (p >> 2);
    const int obase = (p & 3) * 512;
    f4 w[8];
#pragma unroll
    for (int pass = 0; pass < 8; ++pass) {
      const int h = pass * 2 + hsel;
      w[pass] = *(const f4*)(&lds[s_l * 2048 + h * 128 + d]);
    }
#pragma unroll
    for (int pass = 0; pass < 8; ++pass) {
      const int h = pass * 2 + hsel;
      float* op = outb + (size_t)(h * 256 + tgrp) * 2048u + (unsigned)(obase + o);
      __builtin_nontemporal_store(w[pass], (f4*)op);
    }
    __syncthreads();
  }

  if (which) {
    float* cp = colsum + b * 2048;
    atomicAdd(cp + c0 + 0, acc0.x);
    atomicAdd(cp + c0 + 1, acc0.y);
    atomicAdd(cp + c0 + 2, acc0.z);
    atomicAdd(cp + c0 + 3, acc0.w);
    atomicAdd(cp + c1 + 0, acc1.x);
    atomicAdd(cp + c1 + 1, acc1.y);
    atomicAdd(cp + c1 + 2, acc1.z);
    atomicAdd(cp + c1 + 3, acc1.w);
  }
}

extern "C" void kernel_launch(void* const* d_in, const int* in_sizes, int n_in,
                              void* d_out, int out_size, void* d_ws, size_t ws_size,
                              hipStream_t stream) {
  const float* x      = (const float*)d_in[0];
  const float* K_his  = (const float*)d_in[1];
  const float* V_his  = (const float*)d_in[2];
  const float* W_attn = (const float*)d_in[3];
  const float* b_attn = (const float*)d_in[4];
  const float* W_proj = (const float*)d_in[5];
  const float* b_proj = (const float*)d_in[6];

  float* out    = (float*)d_out;
  float* qkv    = (float*)d_ws;            // 16*4096 f32 = 256 KB
  float* colsum = qkv + 16 * 4096;         // 16*2048 f32 = 128 KB
  float* vnext  = out + 268435456ull;      // third output region

  init_kernel<<<256, 256, 0, stream>>>(b_attn, b_proj, qkv, colsum, vnext);
  small_gemm_atomic<<<dim3(8, 32), 256, 0, stream>>>(x, W_attn, 6144, 2048, qkv, 4096);
  copy_transpose<<<dim3(32, 16, 2), 256, 0, stream>>>(K_his, V_his, qkv, out, colsum);
  small_gemm_atomic<<<dim3(4, 32), 256, 0, stream>>>(colsum, W_proj, 2048, 0, vnext, 2048);
}